// Round 5
// baseline (3262.761 us; speedup 1.0000x reference)
//
#include <hip/hip_runtime.h>

// 2D-MDLSTM wavefront kernel for MI355X (gfx950), full hi/lo f16-split precision.
// z = [x(256) | h_up(512) | h_left(512)] @ W(1280x2560) + b, gates i,j,f1,f2,o.
// Split: every operand O = Oh + Ol (f16 pair); z-term = AhBh + AlBh + AhBl (fp32 acc).
// Scaling: A-planes *16, B-planes *64; z = acc/1024 + b.
// Round 5: h = write-once full array (sc0sc1 stores, PLAIN cached loads -- no address
// is ever loaded before its unique write, so no stale-L2 hazard; per-XCD L2 dedups
// the 4 subslice readers). c = 2-slot ring, nt loads (one slice reads each element).
// Grid 1024 = 32 slices x 32 cellgroups, 4 WGs/CU (LDS 4x40KB = 160KB exactly).

typedef _Float16 f16;
typedef f16   f16x8 __attribute__((ext_vector_type(8)));
typedef float f32x4 __attribute__((ext_vector_type(4)));

#define SCL (1.0f/1024.0f)

// workspace layout (bytes); total ~118.1 MiB
#define FLAGS_OFF  0L
#define FLAGS2_OFF 4096L                // (d*8+grp)*16 ints, 64B-padded counters (32KB)
#define ZERO_OFF   40960L               // ~88 KB zero block (memset prefix covers it)
#define BT_OFF     131072L
#define BT_BYTES   13107200L            // 409600 frags * 16 f16 * 2B (hi/lo interleaved)
#define XG_OFF     (BT_OFF + BT_BYTES)
#define XG_PLANE   8388608L             // elems per plane (1024*32*256)
#define XG_BYTES   (XG_PLANE*4L)
#define HR_OFF     (XG_OFF + XG_BYTES)
#define HR_PLANE   16777216L            // elems per plane (1024*32*512) -- FULL array
#define HR_BYTES   (HR_PLANE*4L)        // 67 MB (hi+lo planes)
#define CR_OFF     (HR_OFF + HR_BYTES)
#define CR_BYTES   (2L*32*16384*4)      // 4 MB c ring (2 diag slots)

// ---------------- prep: gather x -> xg f16 hi/lo planes [cell][b][f] ----------------
__global__ __launch_bounds__(256) void gather_xg_k(const float* __restrict__ x, f16* __restrict__ xg) {
  int cb = blockIdx.x;                  // cell*32 + b
  int f  = threadIdx.x;
  int cell = cb >> 5, b = cb & 31;
  int hh = cell >> 5, ww = cell & 31;
  int c  = f & 15, fo = f >> 4;
  int xd = hh*4 + (ww >> 3);
  int yd = (ww & 7)*16 + fo;
  float v = x[(((long)b*16 + c)*128 + xd)*128 + yd] * 16.0f;
  f16 hi = (f16)v;
  f16 lo = (f16)(v - (float)hi);
  long o = (long)cb*256 + f;
  xg[o] = hi;
  xg[XG_PLANE + o] = lo;
}

// ---------------- prep: W -> f16 hi/lo frag pairs, column-permuted ----------------
__global__ __launch_bounds__(256) void prep_b_k(const float* __restrict__ Wm, f16* __restrict__ Bt) {
  int idx = blockIdx.x*256 + threadIdx.x;   // 0..409599
  int lane = idx & 63;
  int t    = idx >> 6;
  int kstep = t % 40, ntile = t / 40;
  int s = ntile / 5, g = ntile % 5;
  int n = g*512 + s*16 + (lane & 15);
  int k = kstep*32 + (lane >> 4)*8;
  f16x8 vh, vl;
#pragma unroll
  for (int u = 0; u < 8; ++u) {
    float w = Wm[(long)(k+u)*2560 + n] * 64.0f;
    f16 hi = (f16)w;
    vh[u] = hi;
    vl[u] = (f16)(w - (float)hi);
  }
  ((f16x8*)Bt)[(long)idx*2]     = vh;
  ((f16x8*)Bt)[(long)idx*2 + 1] = vl;
}

__device__ __forceinline__ float sigf(float x) { return 1.0f/(1.0f + __expf(-x)); }
__device__ __forceinline__ float tanh_fast(float x) {
  float e = __expf(-2.0f*fabsf(x));
  float t = (1.0f - e)/(1.0f + e);
  return x >= 0.0f ? t : -t;
}

__device__ __forceinline__ float ld_ntf(const float* p) {
  return __builtin_nontemporal_load(p);
}
// system-scope write-through stores (drained by vmcnt(0) before flag release)
__device__ __forceinline__ void st_sc_f32(float* p, float v) {
  asm volatile("global_store_dword %0, %1, off sc0 sc1" :: "v"(p), "v"(v) : "memory");
}
__device__ __forceinline__ void st_sc_f16(f16* p, f16 v) {
  unsigned v32 = (unsigned)__builtin_bit_cast(unsigned short, v);
  asm volatile("global_store_short %0, %1, off sc0 sc1" :: "v"(p), "v"(v32) : "memory");
}

// A prefetch for global kstep PF: 2 m-tiles x hi/lo. All PLAIN cached loads
// (h addresses are write-once and only read post-flag => L2-safe).
#define PREFA(PF, A0H, A0L, A1H, A1L)                                         \
  { const int pfa_ = (PF);                                                    \
    if (pfa_ < 8) {                                                           \
      const int o_ = pfa_*32 + l4*8;                                          \
      A0H = *(const f16x8*)(pxh + l15*256 + o_);                              \
      A0L = *(const f16x8*)(pxl + l15*256 + o_);                              \
      A1H = *(const f16x8*)(pxh + (16+l15)*256 + o_);                         \
      A1L = *(const f16x8*)(pxl + (16+l15)*256 + o_);                         \
    } else {                                                                  \
      const f16 *qh_, *ql_; int kl_;                                          \
      if (pfa_ < 24) { kl_ = (pfa_-8)*32;  qh_ = puh; ql_ = pul; }            \
      else           { kl_ = (pfa_-24)*32; qh_ = plh; ql_ = pll; }            \
      const int o_ = kl_ + l4*8;                                              \
      A0H = *(const f16x8*)(qh_ + l15*512 + o_);                              \
      A0L = *(const f16x8*)(ql_ + l15*512 + o_);                              \
      A1H = *(const f16x8*)(qh_ + (16+l15)*512 + o_);                         \
      A1L = *(const f16x8*)(ql_ + (16+l15)*512 + o_);                         \
    } }

#define PREFB(PF)                                                             \
  { const int pfb_ = (PF);                                                    \
    _Pragma("unroll")                                                         \
    for (int g = 0; g < 5; ++g) {                                             \
      const long b2_ = ((long)bfbase + g*2560 + pfb_*64)*2;                   \
      Bh[g] = Bf[b2_]; Bl[g] = Bf[b2_+1];                                     \
    } }

#define MFMAS(A0H, A0L, A1H, A1L)                                             \
  _Pragma("unroll")                                                           \
  for (int g = 0; g < 5; ++g) {                                               \
    acc[0][g] = __builtin_amdgcn_mfma_f32_16x16x32_f16(A0H, Bh[g], acc[0][g], 0,0,0); \
    acc[0][g] = __builtin_amdgcn_mfma_f32_16x16x32_f16(A0L, Bh[g], acc[0][g], 0,0,0); \
    acc[0][g] = __builtin_amdgcn_mfma_f32_16x16x32_f16(A0H, Bl[g], acc[0][g], 0,0,0); \
    acc[1][g] = __builtin_amdgcn_mfma_f32_16x16x32_f16(A1H, Bh[g], acc[1][g], 0,0,0); \
    acc[1][g] = __builtin_amdgcn_mfma_f32_16x16x32_f16(A1L, Bh[g], acc[1][g], 0,0,0); \
    acc[1][g] = __builtin_amdgcn_mfma_f32_16x16x32_f16(A1H, Bl[g], acc[1][g], 0,0,0); \
  }

// ---------------- main persistent wavefront kernel ----------------
// 1024 WGs x 256 thr (4 WGs/CU). wid: xcd=wid&7, u=wid>>3 (0..127),
// subslice=u&3 -> slice s=subslice*8+xcd (B pinned to XCD L2), cellgroup=u>>2 (0..31).
// WG-task = (cell, slice); 4 waves = 4 K-chunks of 320 (10 ksteps each);
// LDS reduce partials; waves 0/1 epilogue (m-halves).
__global__ __launch_bounds__(256, 4) void mdlstm_wave_k(
    const f16* __restrict__ Bt, const f16* __restrict__ xg,
    f16* __restrict__ hr, float* __restrict__ cr,
    const float* __restrict__ bias, const f16* __restrict__ zb,
    float* __restrict__ out, int* __restrict__ flags, int* __restrict__ flags2)
{
  const int wid = blockIdx.x;
  const int xcd = wid & 7, u = wid >> 3;
  const int subslice = u & 3, cellgroup = u >> 2;
  const int s = subslice*8 + xcd, r0 = s*16;
  const int grp8 = wid >> 7;                 // 0..7
  const bool leader = (wid & 127) == 0;
  const int tid = threadIdx.x, wave = tid >> 6, lane = tid & 63;
  const int l15 = lane & 15, l4 = lane >> 4;
  const f16x8* __restrict__ Bf = (const f16x8*)Bt;
  const int bfbase = s*12800 + lane;         // frag idx = bfbase + g*2560 + ks*64
  const int kb = wave*10;                    // this wave's K-chunk base kstep

  __shared__ f32x4 lred[4][10][64];

  float bia[5];
#pragma unroll
  for (int g = 0; g < 5; ++g) bia[g] = bias[g*512 + r0 + l15];

  for (int d = 0; d < 63; ++d) {
    if (d > 0) {
      if (tid == 0) {
        if (leader) {
          while (__hip_atomic_load(&flags2[((d-1)*8 + grp8)*16], __ATOMIC_RELAXED, __HIP_MEMORY_SCOPE_AGENT) < 128)
            __builtin_amdgcn_s_sleep(2);
          __hip_atomic_fetch_add(&flags[d-1], 1, __ATOMIC_RELAXED, __HIP_MEMORY_SCOPE_AGENT);
        }
        while (__hip_atomic_load(&flags[d-1], __ATOMIC_RELAXED, __HIP_MEMORY_SCOPE_AGENT) < 8)
          __builtin_amdgcn_s_sleep(2);
      }
      __syncthreads();
    }
    const int ncell = (d < 32) ? (d + 1) : (63 - d);
    const int i0    = (d < 32) ? 0 : (d - 31);
    const int rprev = ((d-1)&1)*32;
    const int L     = cellgroup;

    if (L < ncell) {
      const int i = i0 + L, j = d - i;
      const long cid = (long)i*32 + j;
      const f16 *pxh = xg + cid*8192, *pxl = xg + XG_PLANE + cid*8192;
      // h full array: plain cached loads (write-once protocol)
      const f16 *puh = (i>0) ? (hr + (cid-32)*16384) : zb;
      const f16 *pul = (i>0) ? (hr + HR_PLANE + (cid-32)*16384) : zb;
      const f16 *plh = (j>0) ? (hr + (cid-1)*16384) : zb;
      const f16 *pll = (j>0) ? (hr + HR_PLANE + (cid-1)*16384) : zb;

      // hoisted c-ring preloads for epilogue (nt; latency hides under K-loop)
      float cu_r[4], cl_r[4];
      if (wave < 2) {
#pragma unroll
        for (int v = 0; v < 4; ++v) {
          const int off = (wave*16 + l4*4 + v)*512 + r0 + l15;
          cu_r[v] = (i>0) ? ld_ntf(cr + (long)(rprev+i-1)*16384 + off) : 0.0f;
          cl_r[v] = (j>0) ? ld_ntf(cr + (long)(rprev+i)*16384 + off)   : 0.0f;
        }
      }

      f32x4 acc[2][5];
#pragma unroll
      for (int mt = 0; mt < 2; ++mt)
#pragma unroll
        for (int g = 0; g < 5; ++g) acc[mt][g] = (f32x4){0.f,0.f,0.f,0.f};

      f16x8 Bh[5], Bl[5];
      f16x8 c0h, c0l, c1h, c1l, n0h, n0l, n1h, n1l;
      PREFA(kb, c0h, c0l, c1h, c1l);
#pragma unroll
      for (int t = 0; t < 10; t += 2) {
        PREFA(kb+t+1, n0h, n0l, n1h, n1l);
        PREFB(kb+t);
        MFMAS(c0h, c0l, c1h, c1l);
        if (t+2 < 10) PREFA(kb+t+2, c0h, c0l, c1h, c1l);
        PREFB(kb+t+1);
        MFMAS(n0h, n0l, n1h, n1l);
      }

      // ---- LDS reduction of 4 K-chunk partials ----
#pragma unroll
      for (int mt = 0; mt < 2; ++mt)
#pragma unroll
        for (int g = 0; g < 5; ++g)
          lred[wave][mt*5+g][lane] = acc[mt][g];
      __syncthreads();

      if (wave < 2) {
        f32x4 sum[5];
#pragma unroll
        for (int g = 0; g < 5; ++g)
          sum[g] = lred[0][wave*5+g][lane] + lred[1][wave*5+g][lane]
                 + lred[2][wave*5+g][lane] + lred[3][wave*5+g][lane];

        const long wbc = (long)((d&1)*32 + i)*16384;   // c ring slot
        const long wbh = cid*16384;                    // h full array
#pragma unroll
        for (int v = 0; v < 4; ++v) {
          const int brow = wave*16 + l4*4 + v;
          const int off = brow*512 + r0 + l15;
          float zi  = sum[0][v]*SCL + bia[0];
          float zj  = sum[1][v]*SCL + bia[1];
          float zf1 = sum[2][v]*SCL + bia[2];
          float zf2 = sum[3][v]*SCL + bia[3];
          float zo  = sum[4][v]*SCL + bia[4];
          float nc = cu_r[v]*sigf(zf1) + cl_r[v]*sigf(zf2) + sigf(zi)*tanh_fast(zj);
          float nh = tanh_fast(nc)*sigf(zo);
          st_sc_f32(cr + wbc + off, nc);
          float nhs = nh * 16.0f;
          f16 hh = (f16)nhs;
          st_sc_f16(hr + wbh + off, hh);
          st_sc_f16(hr + HR_PLANE + wbh + off, (f16)(nhs - (float)hh));
          __builtin_nontemporal_store(nh, out + (((long)brow*32 + i)*32 + j)*512 + r0 + l15);
        }
      }
    }

    // ---- end of diagonal: drain all vmem (incl. sc stores), then signal ----
    asm volatile("s_waitcnt vmcnt(0)" ::: "memory");
    __syncthreads();
    if (tid == 0)
      __hip_atomic_fetch_add(&flags2[(d*8 + grp8)*16], 1, __ATOMIC_RELAXED, __HIP_MEMORY_SCOPE_AGENT);
  }
}

extern "C" void kernel_launch(void* const* d_in, const int* in_sizes, int n_in,
                              void* d_out, int out_size, void* d_ws, size_t ws_size,
                              hipStream_t stream) {
  const float* x  = (const float*)d_in[0];   // [32,16,128,128]
  const float* Wm = (const float*)d_in[1];   // [1280,2560]
  const float* bs = (const float*)d_in[2];   // [2560]
  float* out = (float*)d_out;                // [32,32,32,512]
  char* ws = (char*)d_ws;                    // needs ~118.1 MiB

  int*   flags  = (int*)(ws + FLAGS_OFF);
  int*   flags2 = (int*)(ws + FLAGS2_OFF);
  f16*   zb     = (f16*)(ws + ZERO_OFF);
  f16*   Bt     = (f16*)(ws + BT_OFF);
  f16*   xgb    = (f16*)(ws + XG_OFF);
  f16*   hrb    = (f16*)(ws + HR_OFF);
  float* crb    = (float*)(ws + CR_OFF);

  hipMemsetAsync(ws, 0, BT_OFF, stream);     // flags + flags2 + zero block
  gather_xg_k<<<32768, 256, 0, stream>>>(x, xgb);
  prep_b_k<<<1600, 256, 0, stream>>>(Wm, Bt);
  mdlstm_wave_k<<<1024, 256, 0, stream>>>(Bt, xgb, hrb, crb, bs, zb, out, flags, flags2);
}